// Round 2
// baseline (418.865 us; speedup 1.0000x reference)
//
#include <hip/hip_runtime.h>
#include <cmath>

constexpr int    NCY   = 150;
constexpr int    BATCH = 65536;
constexpr size_t NB    = (size_t)NCY * (size_t)BATCH;
constexpr float  MU_MIN = 0.1f;
constexpr float  MU_MAX = 1.3f;
constexpr float  T_REFC = 160.0f;

// softplus(x) = logaddexp(x, 0) = max(x,0) + log1p(exp(-|x|))  (numpy's algorithm)
__device__ __forceinline__ float softplus_stable(float x) {
#pragma clang fp contract(off)
    return fmaxf(x, 0.0f) + log1pf(expf(-fabsf(x)));
}

struct StepStats { float pi, d1, s1, d2, s2; };

// IDENTICAL expression trees in both kernels (fp contract off) so phase-2's
// recomputed pi is bitwise equal to phase-1's -> branch decisions agree.
__device__ __forceinline__ StepStats step_stats(float mu,
        float A, float a_mu, float a_mu2,
        float c0, float c_mu, float ct,
        float s0, float s_mu, float st,
        float j0, float j_mu, float jt,
        float v0, float v_mu) {
#pragma clang fp contract(off)
    StepStats r;
    const float x_pi = (A + a_mu * mu) + (a_mu2 * mu) * mu;
    r.pi = 1.0f / (1.0f + expf(-x_pi));
    r.d1 = (c0 + c_mu * mu) + ct;
    r.s1 = softplus_stable((s0 + s_mu * mu) + st);
    r.d2 = (j0 + j_mu * mu) + jt;
    r.s2 = softplus_stable(v0 + v_mu * mu);
    return r;
}

// ---------------- Phase 1: sequential recurrence, writes ONLY mu_hist ----------------
__global__ __launch_bounds__(256)
void galling_p1(const float* __restrict__ params,
                const float* __restrict__ Tptr,
                const float* __restrict__ u,
                const float* __restrict__ noise,
                float* __restrict__ out)   // out[0..NB) = mu_hist
{
#pragma clang fp contract(off)
    const int b = blockIdx.x * blockDim.x + threadIdx.x;

    const float a0   = params[0],  a_T  = params[1],  a_mu = params[2],  a_mu2 = params[3];
    const float c0   = params[4],  c_mu = params[5],  c_T  = params[6];
    const float s0   = params[7],  s_mu = params[8],  s_T  = params[9];
    const float j0   = params[10], j_mu = params[11], j_T  = params[12];
    const float v0   = params[13], v_mu = params[14];
    const float mu0_base = params[15], mu0_T = params[16];

    const float dT = Tptr[0] - T_REFC;
    const float A  = a0 + a_T * dT;
    const float ct = c_T * dT;
    const float st = s_T * dT;
    const float jt = j_T * dT;

    float mu = fminf(fmaxf(mu0_base + mu0_T * dT, MU_MIN), MU_MAX);

    const float* up  = u     + b;
    const float* npp = noise + b;

    // 4-deep circular prefetch: load for t+4 issued at iter t (~4 iters * ~250cyc
    // coverage > ~900cyc HBM latency). unroll 4 makes t&3 a compile-time index.
    float uf[4], nf[4];
#pragma unroll
    for (int i = 0; i < 4; ++i) {
        uf[i] = up [(size_t)i * BATCH];
        nf[i] = npp[(size_t)i * BATCH];
    }

#pragma unroll 4
    for (int t = 0; t < NCY; ++t) {
        const float u_cur = uf[t & 3];
        const float n_cur = nf[t & 3];
        const int tp = (t + 4 < NCY) ? (t + 4) : (NCY - 1);
        uf[t & 3] = up [(size_t)tp * BATCH];
        nf[t & 3] = npp[(size_t)tp * BATCH];

        const StepStats s = step_stats(mu, A, a_mu, a_mu2, c0, c_mu, ct,
                                       s0, s_mu, st, j0, j_mu, jt, v0, v_mu);
        const bool  stay    = u_cur < s.pi;
        const float delta   = stay ? (s.d1 + s.s1 * n_cur) : (s.d2 + s.s2 * n_cur);
        const float mu_next = fminf(fmaxf(mu + delta, MU_MIN), MU_MAX);

        out[(size_t)t * BATCH + b] = mu_next;   // single coalesced 4B store per iter
        mu = mu_next;
    }
}

// ---------------- Phase 2: embarrassingly parallel stat recomputation ----------------
// Grid: (BATCH/256, 38). Each thread: chain b, timesteps t0..t0+3 (t0 = 4*blockIdx.y).
__global__ __launch_bounds__(256)
void galling_p2(const float* __restrict__ params,
                const float* __restrict__ Tptr,
                const float* __restrict__ u,
                float* __restrict__ out)
{
#pragma clang fp contract(off)
    const int b  = blockIdx.x * blockDim.x + threadIdx.x;
    const int t0 = blockIdx.y * 4;
    const int nt = (t0 + 4 <= NCY) ? 4 : (NCY - t0);

    const float a0   = params[0],  a_T  = params[1],  a_mu = params[2],  a_mu2 = params[3];
    const float c0   = params[4],  c_mu = params[5],  c_T  = params[6];
    const float s0   = params[7],  s_mu = params[8],  s_T  = params[9];
    const float j0   = params[10], j_mu = params[11], j_T  = params[12];
    const float v0   = params[13], v_mu = params[14];
    const float mu0_base = params[15], mu0_T = params[16];

    const float dT = Tptr[0] - T_REFC;
    const float A  = a0 + a_T * dT;
    const float ct = c_T * dT;
    const float st = s_T * dT;
    const float jt = j_T * dT;

    const float* mu_hist = out;  // phase 1 wrote out[0..NB)

    float mu_prev = (t0 == 0)
        ? fminf(fmaxf(mu0_base + mu0_T * dT, MU_MIN), MU_MAX)
        : mu_hist[(size_t)(t0 - 1) * BATCH + b];

    float muc[4], uc[4];
#pragma unroll
    for (int i = 0; i < 4; ++i) {
        if (i < nt) {
            const size_t base = (size_t)(t0 + i) * BATCH + b;
            muc[i] = mu_hist[base];
            uc[i]  = u[base];
        }
    }

#pragma unroll
    for (int i = 0; i < 4; ++i) {
        if (i < nt) {
            const StepStats s = step_stats(mu_prev, A, a_mu, a_mu2, c0, c_mu, ct,
                                           s0, s_mu, st, j0, j_mu, jt, v0, v_mu);
            const float comp = (uc[i] < s.pi) ? 0.0f : 1.0f;
            const size_t base = (size_t)(t0 + i) * BATCH + b;
            out[1 * NB + base] = comp;
            out[2 * NB + base] = s.pi;
            out[3 * NB + base] = s.d1;
            out[4 * NB + base] = s.s1;
            out[5 * NB + base] = s.d2;
            out[6 * NB + base] = s.s2;
            mu_prev = muc[i];
        }
    }
}

extern "C" void kernel_launch(void* const* d_in, const int* in_sizes, int n_in,
                              void* d_out, int out_size, void* d_ws, size_t ws_size,
                              hipStream_t stream) {
    const float* params = (const float*)d_in[0];
    const float* Tptr   = (const float*)d_in[1];
    const float* u      = (const float*)d_in[2];
    const float* noise  = (const float*)d_in[3];
    float*       out    = (float*)d_out;

    galling_p1<<<dim3(BATCH / 256), dim3(256), 0, stream>>>(params, Tptr, u, noise, out);
    galling_p2<<<dim3(BATCH / 256, (NCY + 3) / 4), dim3(256), 0, stream>>>(params, Tptr, u, out);
}

// Round 3
// 367.987 us; speedup vs baseline: 1.1383x; 1.1383x over previous
//
#include <hip/hip_runtime.h>
#include <cmath>

constexpr int    NCY   = 150;
constexpr int    BATCH = 65536;
constexpr size_t NB    = (size_t)NCY * (size_t)BATCH;
constexpr float  MU_MIN = 0.1f;
constexpr float  MU_MAX = 1.3f;
constexpr float  T_REFC = 160.0f;

// softplus(x) = logaddexp(x, 0) = max(x,0) + log1p(exp(-|x|))  (numpy's algorithm)
__device__ __forceinline__ float softplus_stable(float x) {
#pragma clang fp contract(off)
    return fmaxf(x, 0.0f) + log1pf(expf(-fabsf(x)));
}

// Monolithic kernel: one thread per chain, 150 sequential steps, 7 coalesced
// streaming stores per step. BW-bound: 354 MB total traffic -> ~56 us floor.
// (R2's two-phase split added 78 MB re-reads + a launch gap: net -11 us by reverting.)
__global__ __launch_bounds__(256)
void galling_sim_kernel(const float* __restrict__ params,
                        const float* __restrict__ Tptr,
                        const float* __restrict__ u,
                        const float* __restrict__ noise,
                        float* __restrict__ out)
{
    // numpy rounds every op; forbid FMA contraction to match op-by-op fp32 rounding
    // (branch u < pi is bit-sensitive).
#pragma clang fp contract(off)

    const int b = blockIdx.x * blockDim.x + threadIdx.x;

    const float a0   = params[0],  a_T  = params[1],  a_mu = params[2],  a_mu2 = params[3];
    const float c0   = params[4],  c_mu = params[5],  c_T  = params[6];
    const float s0   = params[7],  s_mu = params[8],  s_T  = params[9];
    const float j0   = params[10], j_mu = params[11], j_T  = params[12];
    const float v0   = params[13], v_mu = params[14];
    const float mu0_base = params[15], mu0_T = params[16];

    const float dT = Tptr[0] - T_REFC;
    const float A  = a0 + a_T * dT;
    const float ct = c_T * dT;
    const float st = s_T * dT;
    const float jt = j_T * dT;

    float mu = fminf(fmaxf(mu0_base + mu0_T * dT, MU_MIN), MU_MAX);

    const float* up  = u     + b;
    const float* npp = noise + b;
    float*       o   = out   + b;

    // 4-deep circular prefetch for the two input streams.
    float uf[4], nf[4];
#pragma unroll
    for (int i = 0; i < 4; ++i) {
        uf[i] = up [(size_t)i * BATCH];
        nf[i] = npp[(size_t)i * BATCH];
    }

#pragma unroll 4
    for (int t = 0; t < NCY; ++t) {
        const float u_cur = uf[t & 3];
        const float n_cur = nf[t & 3];
        const int tp = (t + 4 < NCY) ? (t + 4) : (NCY - 1);
        uf[t & 3] = up [(size_t)tp * BATCH];
        nf[t & 3] = npp[(size_t)tp * BATCH];

        // pi = sigmoid(((a0 + a_T*dT) + a_mu*mu) + (a_mu2*mu)*mu)
        const float x_pi = (A + a_mu * mu) + (a_mu2 * mu) * mu;
        const float pi   = 1.0f / (1.0f + expf(-x_pi));
        const float d1 = (c0 + c_mu * mu) + ct;
        const float sigma1 = softplus_stable((s0 + s_mu * mu) + st);
        const float d2 = (j0 + j_mu * mu) + jt;
        const float sigma2 = softplus_stable(v0 + v_mu * mu);

        const bool  stay      = u_cur < pi;
        const float component = stay ? 0.0f : 1.0f;
        const float delta     = stay ? (d1 + sigma1 * n_cur) : (d2 + sigma2 * n_cur);
        const float mu_next   = fminf(fmaxf(mu + delta, MU_MIN), MU_MAX);

        // 7 streaming (non-temporal) stores: written once, never re-read by us.
        // 'nt' keeps the 275 MB write stream from thrashing L2/L3, leaving the
        // L3 warm for the u/noise reads (78 MB, restored via L2/L3 each iter).
        float* p = o + (size_t)t * BATCH;
        __builtin_nontemporal_store(mu_next,   p + 0 * NB);
        __builtin_nontemporal_store(component, p + 1 * NB);
        __builtin_nontemporal_store(pi,        p + 2 * NB);
        __builtin_nontemporal_store(d1,        p + 3 * NB);
        __builtin_nontemporal_store(sigma1,    p + 4 * NB);
        __builtin_nontemporal_store(d2,        p + 5 * NB);
        __builtin_nontemporal_store(sigma2,    p + 6 * NB);

        mu = mu_next;
    }
}

extern "C" void kernel_launch(void* const* d_in, const int* in_sizes, int n_in,
                              void* d_out, int out_size, void* d_ws, size_t ws_size,
                              hipStream_t stream) {
    const float* params = (const float*)d_in[0];
    const float* Tptr   = (const float*)d_in[1];
    const float* u      = (const float*)d_in[2];
    const float* noise  = (const float*)d_in[3];
    float*       out    = (float*)d_out;

    galling_sim_kernel<<<dim3(BATCH / 256), dim3(256), 0, stream>>>(params, Tptr, u, noise, out);
}